// Round 15
// baseline (37.259 us; speedup 1.0000x reference)
//
#include <hip/hip_runtime.h>
#include <math.h>

// LightconvLayer: x (T,B,C) f32, weight (H,K) f32 -> out (T,B,C) f32
// out[t,b,c] = sum_k softmax(weight[c/64])[k] * x[t+k-30, b, c] (zero-pad left)
//
// R15: PRODUCER/CONSUMER WAVE SPECIALIZATION (store-decoupled vmcnt queues).
// gfx9 vmcnt retires in-order across loads AND stores of one wave; R8-R12's
// counted load-waits therefore drained old HBM stores (the ~80% stall).
// Fix: separate queues by WAVE.
//  - block = 192 thr = 3 waves owns (b, 128 ch, 64-row chunk)
//    wave 0 producer: ONLY global_load_lds; counted vmcnt(8) on pure-load
//      queue (exact L(j) retirement, store-independent); s_barrier per tile.
//    waves 1,2 consumers: ch-halves (one head each -> SGPR taps); 38-row f32
//      sliding register window; per tile: s_barrier, 8x ds_read_b32 (2-way
//      bank = free), 248 FMA, 8 dword stores. NO vmcnt wait ever - stores
//      drain at kernel end only.
//  - ring[32][128] f32 = 16 KB -> 10 blocks/CU (30 waves).
//  - slot safety: L(j+2) slots (8j+16..23)&31 vs consumer reads of tiles
//    j-1,j (8j-8..8j+7)&31 - disjoint; barrier-per-tile orders the rest.
//  - producer ledger (loads only): j<=5 wait vmcnt(8) [L(j+1),L(j+2) in
//    flight], j=6 vmcnt(4), j=7 vmcnt(0). Prologue stages L(0),L(1).
#define T_LEN 2048
#define B_SZ  8
#define C_SZ  1024
#define NH    16
#define KW    31
#define HALO  (KW - 1)        // 30
#define TT    8
#define CHUNK 64              // rows per block
#define NTILE (CHUNK / TT)    // 8
#define RING  32
#define WIN   (TT + HALO)     // 38
#define CGW   128             // channels per block
#define ROWSTRIDE (B_SZ * C_SZ)  // 8192 floats between t rows

#define GLOBAL_AS(p) ((const __attribute__((address_space(1))) void*)(p))
#define LDS_AS(p)    ((__attribute__((address_space(3))) void*)(p))

__global__ __launch_bounds__(192, 4) void lightconv_kernel(
    const float* __restrict__ x, const float* __restrict__ weight,
    float* __restrict__ out) {
  __shared__ float ring[RING][CGW];  // 16 KB
  const int tid  = threadIdx.x;
  const int w    = tid >> 6;         // 0 = producer, 1..2 = consumers
  const int lane = tid & 63;

  const int cgrp = blockIdx.x & 7;   // 128-ch group
  const int tc   = blockIdx.x >> 3;  // t-chunk 0..31
  const int b    = blockIdx.y;
  const int c0   = cgrp * CGW;
  const int tb   = tc * CHUNK;       // tb % 32 == 0 -> compile-time slots

  const float* xbase = x + (size_t)b * C_SZ + c0;

  if (w == 0) {
    // ================= PRODUCER: pure-load vmcnt queue =================
    const int lane_off = (lane >> 5) * ROWSTRIDE + (lane & 31) * 4;
    // prologue: L(0),L(1) = rows tb..tb+15 -> slots 0..15 (8 instrs)
#pragma unroll
    for (int r2 = 0; r2 < 8; ++r2) {
      const float* gp = xbase + (size_t)(tb + 2 * r2) * ROWSTRIDE + lane_off;
      __builtin_amdgcn_global_load_lds(GLOBAL_AS(gp), LDS_AS(&ring[2 * r2][0]),
                                       16, 0, 0);
    }
#pragma unroll
    for (int j = 0; j < NTILE; ++j) {
      __builtin_amdgcn_sched_barrier(0);
      if (j <= NTILE - 3) {
        // stage L(j+2): rows tb+(j+2)*8 .. +7 -> slots (8j+16+2r2)&31
#pragma unroll
        for (int r2 = 0; r2 < 4; ++r2) {
          const float* gp =
              xbase + (size_t)(tb + (j + 2) * TT + 2 * r2) * ROWSTRIDE + lane_off;
          __builtin_amdgcn_global_load_lds(
              GLOBAL_AS(gp), LDS_AS(&ring[(8 * j + 16 + 2 * r2) & (RING - 1)][0]),
              16, 0, 0);
        }
      }
      // counted wait on PURE-LOAD queue: L(j) retired
      if (j <= NTILE - 3)      asm volatile("s_waitcnt vmcnt(8)" ::: "memory");
      else if (j == NTILE - 2) asm volatile("s_waitcnt vmcnt(4)" ::: "memory");
      else                     asm volatile("s_waitcnt vmcnt(0)" ::: "memory");
      __builtin_amdgcn_sched_barrier(0);
      __builtin_amdgcn_s_barrier();     // tile j ready for consumers
    }
  } else {
    // ================= CONSUMERS: no vmcnt waits, stores drain lazily ====
    const int choff = (w - 1) * 64;    // channel half within the 128
    const int head  = cgrp * 2 + (w - 1);  // wave-uniform -> SGPR taps

    float wv[KW];
    float m = -1e30f;
#pragma unroll
    for (int k = 0; k < KW; ++k) {
      wv[k] = weight[head * KW + k];   // uniform -> s_load
      m = fmaxf(m, wv[k]);
    }
    float s = 0.f;
#pragma unroll
    for (int k = 0; k < KW; ++k) {
      wv[k] = expf(wv[k] - m);
      s += wv[k];
    }
    const float inv = 1.f / s;
    float wk[KW];
#pragma unroll
    for (int k = 0; k < KW; ++k) {
      wk[k] = __uint_as_float(
          __builtin_amdgcn_readfirstlane(__float_as_uint(wv[k] * inv)));
    }

    // halo rows tb-30..tb-1 -> register window (loads retire in prologue,
    // before any store exists in this wave's queue)
    const float* xch = xbase + choff + lane;
    float xv[WIN];
    if (tb == 0) {
#pragma unroll
      for (int i = 0; i < HALO; ++i) xv[i] = 0.f;
    } else {
#pragma unroll
      for (int i = 0; i < HALO; ++i) {
        xv[i] = xch[(size_t)(tb - HALO + i) * ROWSTRIDE];
      }
    }

    float* opb = out + ((size_t)tb * B_SZ + b) * C_SZ + c0 + choff + lane;
#pragma unroll
    for (int j = 0; j < NTILE; ++j) {
      __builtin_amdgcn_s_barrier();       // tile j staged
      __builtin_amdgcn_sched_barrier(0);  // don't hoist ds_reads above
      // 8 new rows (slots 8j..8j+7, imm offsets); compiler inserts lgkmcnt
#pragma unroll
      for (int i = 0; i < TT; ++i) {
        xv[HALO + i] = ring[(8 * j + i) & (RING - 1)][choff + lane];
      }
      // 8 outputs; stores are NEVER waited on
#pragma unroll
      for (int o = 0; o < TT; ++o) {
        float a = 0.f;
#pragma unroll
        for (int k = 0; k < KW; ++k) a = fmaf(wk[k], xv[o + k], a);
        opb[(size_t)(j * TT + o) * ROWSTRIDE] = a;
      }
      // slide window (full unroll -> register renaming)
#pragma unroll
      for (int i = 0; i < HALO; ++i) xv[i] = xv[i + TT];
    }
  }
}

extern "C" void kernel_launch(void* const* d_in, const int* in_sizes, int n_in,
                              void* d_out, int out_size, void* d_ws, size_t ws_size,
                              hipStream_t stream) {
  const float* x = (const float*)d_in[0];      // (T,B,C) f32
  const float* w = (const float*)d_in[1];      // (H,K) f32
  float* out = (float*)d_out;                  // (T,B,C) f32
  (void)in_sizes; (void)n_in; (void)out_size; (void)d_ws; (void)ws_size;

  dim3 grid((C_SZ / CGW) * (T_LEN / CHUNK), B_SZ);  // (256, 8) = 2048 blocks
  dim3 block(192);
  lightconv_kernel<<<grid, block, 0, stream>>>(x, w, out);
}